// Round 2
// baseline (4626.719 us; speedup 1.0000x reference)
//
#include <hip/hip_runtime.h>

// Liquid NN: BATCH=64, SEQ=256, IN=512, HID=1024, 2 layers, tau=0.5.
// h0(t) = h0 + a0*2*(tanh(x_t@W0^T + b0 + h0@U0^T) - h0)
// h1(t) = h1 + a1*2*(tanh(h0(t)@W1^T + b1 + h1@U1^T) - h1)
// Output: h1(255) as f32 (64,1024).
//
// Weight-stationary-in-registers f16 MFMA persistent kernel.
//  - Precompute Wx[t][b][c] = x@W0^T + b0 (f16, 32MB ws) with a parallel MFMA GEMM.
//  - Persistent kernel, 48 WGs x 256 thr, PLAIN launch (48 WGs always co-resident
//    on 256 CUs; cooperative launch failed silently on this container):
//      role 0 (WG 0-15):  h0 update  (U0*h0 GEMM + epilogue)        [slot s -> step s]
//      role 1 (WG 16-31): pA = W1*h0(t) partial                     [slot s -> t=s-1]
//      role 2 (WG 32-47): U1*h1(t-1) GEMM + (pA + bias) epilogue    [slot s -> t=s-1]
//    Each wave holds a (64-col x 256-K) f16 weight slice in VGPRs (loaded once).
//    h state (f32) lives in registers of the owning WG; only f16 h is exchanged
//    through ring buffers in global memory with release/acquire flag sync.
//    Data waits are all-thread acquire spins (per-thread L1 invalidate).

typedef _Float16 f16;
typedef _Float16 f16x8 __attribute__((ext_vector_type(8)));
typedef _Float16 f16x4 __attribute__((ext_vector_type(4)));
typedef float    f32x4 __attribute__((ext_vector_type(4)));

#define B_  64
#define S_  256
#define IN_ 512
#define H_  1024

// ---- workspace layout (bytes) ----
static constexpr size_t OFF_WX  = 0;                      // S*B*H f16   = 33554432
static constexpr size_t OFF_X16 = 33554432;               // B*S*IN f16  = 16777216
static constexpr size_t OFF_H0R = 50331648;               // 8*B*H f16   = 1048576
static constexpr size_t OFF_H1R = 51380224;               // 8*B*H f16   = 1048576
static constexpr size_t OFF_PA  = 52428800;               // 4*B*H f32   = 1048576
static constexpr size_t OFF_FLG = 53477376;               // 65536
// total 53542912 bytes

// flag sub-arrays (int index into flg):
//  flag0[257] @0      (target 16)   h0(s) published
//  flag1[257] @512    (target 16)   h1(t) published
//  cons0[257] @1024   (target 32)   h0(s) consumed (role0 + role1)
//  cons1[257] @1536   (target 16)   h1(t) consumed (role2)
//  flagA[256*16]@2048 (target 1)    pA(t,slice) published
//  consA[256*16]@6144 (target 1)    pA(t,slice) consumed

// ---------------- kernel 0: x f32 -> f16 ----------------
__global__ void k_cvt_x(const float* __restrict__ x, f16* __restrict__ x16) {
  size_t i = ((size_t)blockIdx.x * 256 + threadIdx.x) * 4;
  float4 v = *(const float4*)(x + i);
  f16x4 o;
  o[0] = (f16)v.x; o[1] = (f16)v.y; o[2] = (f16)v.z; o[3] = (f16)v.w;
  *(f16x4*)(x16 + i) = o;
}

// ---------------- kernel 1: Wx = x @ W0^T + b0 ----------------
// Grid 256 WGs: blockIdx = cslice(16) + 16*rowblock(16). WG: 4 waves, each wave
// owns a c16 slice (B-frags of W0 held in regs, K=512), loops 16 row-tiles of 64
// rows (rows = b*256+t), staging x16 tiles in swizzled LDS.
__global__ __launch_bounds__(256) void k_wx(const f16* __restrict__ x16,
                                            const float* __restrict__ W0,
                                            const float* __restrict__ b0,
                                            f16* __restrict__ wx) {
  __shared__ uint4 xs[4096];  // 64 rows x 64 16B-chunks, chunk' = kc ^ (row&7)
  const int tid = threadIdx.x;
  const int w = tid >> 6, lane = tid & 63;
  const int q = lane >> 4, l15 = lane & 15;
  const int cslice = blockIdx.x & 15;
  const int rblock = blockIdx.x >> 4;
  const int c = cslice * 64 + w * 16 + l15;   // this lane's output column (D col = n)

  // B-frags: B[k][n] = W0[c][k], lane holds k = kf*32 + q*8 + j
  f16x8 Bf[16];
#pragma unroll
  for (int kf = 0; kf < 16; ++kf) {
    const float* p = W0 + (size_t)c * IN_ + kf * 32 + q * 8;
    f16x8 v;
#pragma unroll
    for (int j = 0; j < 8; ++j) v[j] = (f16)p[j];
    Bf[kf] = v;
  }
  const float bias = b0[c];

  for (int rt = 0; rt < 16; ++rt) {
    const int row0 = rblock * 1024 + rt * 64;
    __syncthreads();  // protect previous tile's reads
#pragma unroll
    for (int it = 0; it < 16; ++it) {
      int g = it * 256 + tid;       // 4096 chunks
      int r = g >> 6, kc = g & 63;
      xs[r * 64 + (kc ^ (r & 7))] =
          *(const uint4*)(x16 + (size_t)(row0 + r) * IN_ + kc * 8);
    }
    __syncthreads();
    f32x4 acc[4] = {};
#pragma unroll
    for (int mt = 0; mt < 4; ++mt) {
      const int r = mt * 16 + l15;  // A-frag row
#pragma unroll
      for (int kf = 0; kf < 16; ++kf) {
        uint4 av = xs[r * 64 + ((kf * 4 + q) ^ (r & 7))];
        f16x8 a = *(f16x8*)&av;
        acc[mt] = __builtin_amdgcn_mfma_f32_16x16x32_f16(a, Bf[kf], acc[mt], 0, 0, 0);
      }
    }
    // D[m=row][n=c]: lane holds rows q*4+r, col c
#pragma unroll
    for (int mt = 0; mt < 4; ++mt) {
#pragma unroll
      for (int r = 0; r < 4; ++r) {
        int rowg = row0 + mt * 16 + q * 4 + r;  // = b*256 + t
        int b = rowg >> 8, t = rowg & 255;
        wx[((size_t)t * B_ + b) * H_ + c] = (f16)(acc[mt][r] + bias);
      }
    }
  }
}

// ---------------- persistent recurrent kernel ----------------
__device__ __forceinline__ void waitge(int* p, int target) {
  while (__hip_atomic_load(p, __ATOMIC_ACQUIRE, __HIP_MEMORY_SCOPE_AGENT) < target)
    __builtin_amdgcn_s_sleep(2);
}

// one wave: full 64-batch x 64-col x 256-K slab. A = h f16 [64][1024].
__device__ __forceinline__ void gemm_256(const f16* __restrict__ A, int kbase,
                                         int l15, int q,
                                         const f16x8 (&Bf)[4][8], f32x4 (&acc)[4][4]) {
  f16x8 a[4][8];
#pragma unroll
  for (int mt = 0; mt < 4; ++mt) {
    const f16* ar = A + (size_t)(mt * 16 + l15) * H_ + kbase + q * 8;
#pragma unroll
    for (int kf = 0; kf < 8; ++kf) a[mt][kf] = *(const f16x8*)(ar + kf * 32);
  }
#pragma unroll
  for (int mt = 0; mt < 4; ++mt)
#pragma unroll
    for (int nt = 0; nt < 4; ++nt)
#pragma unroll
      for (int kf = 0; kf < 8; ++kf)
        acc[mt][nt] = __builtin_amdgcn_mfma_f32_16x16x32_f16(a[mt][kf], Bf[nt][kf],
                                                             acc[mt][nt], 0, 0, 0);
}

__global__ __launch_bounds__(256, 1) void k_persist(
    const float* __restrict__ U0, const float* __restrict__ W1,
    const float* __restrict__ U1, const float* __restrict__ alpha0,
    const float* __restrict__ alpha1, const float* __restrict__ b1,
    const f16* __restrict__ wx, f16* h0r, f16* h1r, float* pA, int* flg,
    float* out) {
  // red[kslice][mt*16+nt*4+r][lane] : cross-wave K-partial exchange (2-way banks = free)
  __shared__ float red[4][64][64];
  const int tid = threadIdx.x;
  const int w = tid >> 6, lane = tid & 63;
  const int q = lane >> 4, l15 = lane & 15;
  const int wg = blockIdx.x;
  const int role = wg >> 4, slice = wg & 15;
  const int c0 = slice * 64;
  const int kbase = w * 256;

  int* flag0 = flg;
  int* flag1 = flg + 512;
  int* cons0 = flg + 1024;
  int* cons1 = flg + 1536;
  int* flagA = flg + 2048;
  int* consA = flg + 6144;

  // load weight slice into registers (one-time): B[k][n] = Wm[c][k]
  const float* Wm = (role == 0) ? U0 : (role == 1) ? W1 : U1;
  f16x8 Bf[4][8];
#pragma unroll
  for (int nt = 0; nt < 4; ++nt)
#pragma unroll
    for (int kf = 0; kf < 8; ++kf) {
      const float* p = Wm + (size_t)(c0 + nt * 16 + l15) * H_ + kbase + kf * 32 + q * 8;
      f16x8 v;
#pragma unroll
      for (int j = 0; j < 8; ++j) v[j] = (f16)p[j];
      Bf[nt][kf] = v;
    }

  float hst[16];  // persistent h f32 state: wave w owns batches w*16..w*16+15
#pragma unroll
  for (int i = 0; i < 16; ++i) hst[i] = 0.f;
  float coef[4], biasv[4];
#pragma unroll
  for (int nt = 0; nt < 4; ++nt) {
    int c = c0 + nt * 16 + l15;
    coef[nt]  = ((role == 0) ? alpha0[c] : alpha1[c]) * 2.0f;  // alpha * inv_tau
    biasv[nt] = (role == 2) ? b1[c] : 0.f;
  }

  for (int s = 0; s <= 256; ++s) {
    if (role == 0) {  // ---- h0(s) ----
      if (s == 256) break;
      f32x4 acc[4][4] = {};
      if (s > 0) {
        if (tid == 0 && s >= 8) waitge(cons0 + (s - 8), 32);  // ring overwrite safe
        __syncthreads();
        waitge(flag0 + (s - 1), 16);  // all threads: per-thread acquire
        gemm_256(h0r + (size_t)((s - 1) & 7) * B_ * H_, kbase, l15, q, Bf, acc);
      }
#pragma unroll
      for (int mt = 0; mt < 4; ++mt)
#pragma unroll
        for (int nt = 0; nt < 4; ++nt)
#pragma unroll
          for (int r = 0; r < 4; ++r)
            red[w][mt * 16 + nt * 4 + r][lane] = acc[mt][nt][r];
      __syncthreads();
      if (s > 0 && tid == 0)
        __hip_atomic_fetch_add(cons0 + (s - 1), 1, __ATOMIC_RELAXED, __HIP_MEMORY_SCOPE_AGENT);
      f16* hw = h0r + (size_t)(s & 7) * B_ * H_;
#pragma unroll
      for (int nt = 0; nt < 4; ++nt) {
        int c = c0 + nt * 16 + l15;
#pragma unroll
        for (int r = 0; r < 4; ++r) {
          int v = w * 16 + nt * 4 + r;
          float sum = red[0][v][lane] + red[1][v][lane] + red[2][v][lane] + red[3][v][lane];
          int b = w * 16 + q * 4 + r;
          sum += (float)wx[((size_t)s * B_ + b) * H_ + c];
          float th = tanhf(sum);
          float h = hst[nt * 4 + r];
          h = h + coef[nt] * (th - h);
          hst[nt * 4 + r] = h;
          hw[(size_t)b * H_ + c] = (f16)h;
        }
      }
      __threadfence();
      __syncthreads();
      if (tid == 0)
        __hip_atomic_fetch_add(flag0 + s, 1, __ATOMIC_RELEASE, __HIP_MEMORY_SCOPE_AGENT);

    } else if (role == 1) {  // ---- pA(t) = W1*h0(t) ----
      if (s == 0) continue;
      const int t = s - 1;
      if (tid == 0 && t >= 4) waitge(consA + (t - 4) * 16 + slice, 1);
      __syncthreads();
      waitge(flag0 + t, 16);  // all threads: per-thread acquire
      f32x4 acc[4][4] = {};
      gemm_256(h0r + (size_t)(t & 7) * B_ * H_, kbase, l15, q, Bf, acc);
#pragma unroll
      for (int mt = 0; mt < 4; ++mt)
#pragma unroll
        for (int nt = 0; nt < 4; ++nt)
#pragma unroll
          for (int r = 0; r < 4; ++r)
            red[w][mt * 16 + nt * 4 + r][lane] = acc[mt][nt][r];
      __syncthreads();
      if (tid == 0)
        __hip_atomic_fetch_add(cons0 + t, 1, __ATOMIC_RELAXED, __HIP_MEMORY_SCOPE_AGENT);
      float* pa = pA + (size_t)(t & 3) * B_ * H_;
#pragma unroll
      for (int nt = 0; nt < 4; ++nt) {
        int c = c0 + nt * 16 + l15;
#pragma unroll
        for (int r = 0; r < 4; ++r) {
          int v = w * 16 + nt * 4 + r;
          float sum = red[0][v][lane] + red[1][v][lane] + red[2][v][lane] + red[3][v][lane];
          int b = w * 16 + q * 4 + r;
          pa[(size_t)b * H_ + c] = sum;
        }
      }
      __threadfence();
      __syncthreads();
      if (tid == 0)
        __hip_atomic_fetch_add(flagA + t * 16 + slice, 1, __ATOMIC_RELEASE, __HIP_MEMORY_SCOPE_AGENT);

    } else {  // ---- role 2: h1(t) ----
      if (s == 0) continue;
      const int t = s - 1;
      f32x4 acc[4][4] = {};
      if (t > 0) {
        if (tid == 0 && t >= 8) waitge(cons1 + (t - 8), 16);
        __syncthreads();
        waitge(flag1 + (t - 1), 16);  // all threads: per-thread acquire
        gemm_256(h1r + (size_t)((t - 1) & 7) * B_ * H_, kbase, l15, q, Bf, acc);
      }
#pragma unroll
      for (int mt = 0; mt < 4; ++mt)
#pragma unroll
        for (int nt = 0; nt < 4; ++nt)
#pragma unroll
          for (int r = 0; r < 4; ++r)
            red[w][mt * 16 + nt * 4 + r][lane] = acc[mt][nt][r];
      __syncthreads();
      if (t > 0 && tid == 0)
        __hip_atomic_fetch_add(cons1 + (t - 1), 1, __ATOMIC_RELAXED, __HIP_MEMORY_SCOPE_AGENT);
      waitge(flagA + t * 16 + slice, 1);  // all threads: partner L1A, same c-slice
      const float* pa = pA + (size_t)(t & 3) * B_ * H_;
      f16* hw = h1r + (size_t)(t & 7) * B_ * H_;
#pragma unroll
      for (int nt = 0; nt < 4; ++nt) {
        int c = c0 + nt * 16 + l15;
#pragma unroll
        for (int r = 0; r < 4; ++r) {
          int v = w * 16 + nt * 4 + r;
          float sum = red[0][v][lane] + red[1][v][lane] + red[2][v][lane] + red[3][v][lane];
          int b = w * 16 + q * 4 + r;
          sum += pa[(size_t)b * H_ + c] + biasv[nt];
          float th = tanhf(sum);
          float h = hst[nt * 4 + r];
          h = h + coef[nt] * (th - h);
          hst[nt * 4 + r] = h;
          hw[(size_t)b * H_ + c] = (f16)h;
          if (t == 255) out[(size_t)b * H_ + c] = h;
        }
      }
      __threadfence();
      __syncthreads();
      if (tid == 0) {
        __hip_atomic_fetch_add(consA + t * 16 + slice, 1, __ATOMIC_RELAXED, __HIP_MEMORY_SCOPE_AGENT);
        __hip_atomic_fetch_add(flag1 + t, 1, __ATOMIC_RELEASE, __HIP_MEMORY_SCOPE_AGENT);
      }
    }
  }
}

extern "C" void kernel_launch(void* const* d_in, const int* in_sizes, int n_in,
                              void* d_out, int out_size, void* d_ws, size_t ws_size,
                              hipStream_t stream) {
  const float* x  = (const float*)d_in[0];
  const float* W0 = (const float*)d_in[1];
  const float* U0 = (const float*)d_in[2];
  const float* b0 = (const float*)d_in[3];
  const float* a0 = (const float*)d_in[4];
  const float* W1 = (const float*)d_in[5];
  const float* U1 = (const float*)d_in[6];
  const float* b1 = (const float*)d_in[7];
  const float* a1 = (const float*)d_in[8];
  char* ws = (char*)d_ws;
  f16*   wx  = (f16*)(ws + OFF_WX);
  f16*   x16 = (f16*)(ws + OFF_X16);
  f16*   h0r = (f16*)(ws + OFF_H0R);
  f16*   h1r = (f16*)(ws + OFF_H1R);
  float* pA  = (float*)(ws + OFF_PA);
  int*   flg = (int*)(ws + OFF_FLG);
  float* out = (float*)d_out;

  hipMemsetAsync(flg, 0, 65536, stream);                 // flags must start at 0
  k_cvt_x<<<8192, 256, 0, stream>>>(x, x16);             // 8.39M elems / 4 per thr
  k_wx<<<256, 256, 0, stream>>>(x16, W0, b0, wx);        // parallel Wx GEMM

  // plain launch: 48 WGs (<=2/CU by LDS) on an idle 256-CU device are always
  // co-resident; cooperative launch failed silently on this container.
  k_persist<<<48, 256, 0, stream>>>(U0, W1, U1, a0, a1, b1, wx, h0r, h1r, pA,
                                    flg, out);
}

// Round 3
// 3557.956 us; speedup vs baseline: 1.3004x; 1.3004x over previous
//
#include <hip/hip_runtime.h>

// Liquid NN: BATCH=64, SEQ=256, IN=512, HID=1024, 2 layers, tau=0.5.
// h0(t) = h0 + a0*2*(tanh(x_t@W0^T + b0 + h0@U0^T) - h0)
// h1(t) = h1 + a1*2*(tanh(h0(t)@W1^T + b1 + h1@U1^T) - h1)
// Output: h1(255) as f32 (64,1024).
//
// Weight-stationary-in-registers f16 MFMA persistent kernel, 32 WGs:
//   role 0 (WG 0-15):  h0(s) = EMA(tanh(wx[s] + U0*h0(s-1)))      1 sync hop/step
//   role 1 (WG 16-31): h1(t) = EMA(tanh(b1 + W1*h0(t) + U1*h1(t-1))) 1 hop/step
// Sync: tid0-only RELAXED spin on agent-scope flags (no per-poll cache inv),
// then ONE acquire fence + __syncthreads. Producers publish with a single
// release atomicAdd per WG per step (wbl2 covers the whole XCD's dirty L2).
// h exchanged as f16 through depth-8 ring buffers in workspace.

typedef _Float16 f16;
typedef _Float16 f16x8 __attribute__((ext_vector_type(8)));
typedef float    f32x4 __attribute__((ext_vector_type(4)));

#define B_  64
#define S_  256
#define IN_ 512
#define H_  1024

// ---- workspace layout (bytes) ----
static constexpr size_t OFF_WX  = 0;         // S*B*H f16 = 33554432
static constexpr size_t OFF_H0R = 33554432;  // 8*B*H f16 = 1048576
static constexpr size_t OFF_H1R = 34603008;  // 8*B*H f16 = 1048576
static constexpr size_t OFF_FLG = 35651584;  // 8 KB flags
// flag ints: flag0[256]@0, flag1[256]@512, cons0[256]@1024, cons1[256]@1536

// ---------------- kernel: Wx = x @ W0^T + b0 (f32 in, f16 out) ----------------
// 256 WGs: blockIdx = cslice(16) + 16*rowblock(16). 4 waves/WG, each wave owns a
// 16-col slice (W0 frags in regs, K=512), loops 16 row-tiles of 64 rows
// (row = b*256+t), converting f32->f16 while staging x in swizzled LDS.
__global__ __launch_bounds__(256) void k_wx(const float* __restrict__ x,
                                            const float* __restrict__ W0,
                                            const float* __restrict__ b0,
                                            f16* __restrict__ wx) {
  __shared__ uint4 xs[4096];  // 64 rows x 64 8-half chunks, chunk' = kc ^ (row&7)
  const int tid = threadIdx.x;
  const int w = tid >> 6, lane = tid & 63;
  const int q = lane >> 4, l15 = lane & 15;
  const int cslice = blockIdx.x & 15;
  const int rblock = blockIdx.x >> 4;
  const int c = cslice * 64 + w * 16 + l15;  // output column (D col = n)

  // B-frags: B[k][n] = W0[c][k], lane holds k = kf*32 + q*8 + j
  f16x8 Bf[16];
#pragma unroll
  for (int kf = 0; kf < 16; ++kf) {
    const float* p = W0 + (size_t)c * IN_ + kf * 32 + q * 8;
    f16x8 v;
#pragma unroll
    for (int j = 0; j < 8; ++j) v[j] = (f16)p[j];
    Bf[kf] = v;
  }
  const float bias = b0[c];

  for (int rt = 0; rt < 16; ++rt) {
    const int row0 = rblock * 1024 + rt * 64;
    __syncthreads();  // protect previous tile's reads
#pragma unroll
    for (int it = 0; it < 16; ++it) {
      int g = it * 256 + tid;  // 4096 chunks
      int r = g >> 6, kc = g & 63;
      const float* xp = x + (size_t)(row0 + r) * IN_ + kc * 8;
      float4 v0 = *(const float4*)xp;
      float4 v1 = *(const float4*)(xp + 4);
      f16x8 h;
      h[0] = (f16)v0.x; h[1] = (f16)v0.y; h[2] = (f16)v0.z; h[3] = (f16)v0.w;
      h[4] = (f16)v1.x; h[5] = (f16)v1.y; h[6] = (f16)v1.z; h[7] = (f16)v1.w;
      xs[r * 64 + (kc ^ (r & 7))] = *(uint4*)&h;
    }
    __syncthreads();
    f32x4 acc[4] = {};
#pragma unroll
    for (int mt = 0; mt < 4; ++mt) {
      const int r = mt * 16 + l15;  // A-frag row
#pragma unroll
      for (int kf = 0; kf < 16; ++kf) {
        uint4 av = xs[r * 64 + ((kf * 4 + q) ^ (r & 7))];
        f16x8 a = *(f16x8*)&av;
        acc[mt] = __builtin_amdgcn_mfma_f32_16x16x32_f16(a, Bf[kf], acc[mt], 0, 0, 0);
      }
    }
    // D[m=row][n=c]: lane holds rows q*4+r
#pragma unroll
    for (int mt = 0; mt < 4; ++mt) {
#pragma unroll
      for (int r = 0; r < 4; ++r) {
        int rowg = row0 + mt * 16 + q * 4 + r;  // = b*256 + t
        int b = rowg >> 8, t = rowg & 255;
        wx[((size_t)t * B_ + b) * H_ + c] = (f16)(acc[mt][r] + bias);
      }
    }
  }
}

// ---------------- persistent recurrent kernel ----------------
__device__ __forceinline__ void spin_ge(int* p, int target) {
  // RELAXED poll: no cache invalidate per iteration (acquire fence done once after)
  while (__hip_atomic_load(p, __ATOMIC_RELAXED, __HIP_MEMORY_SCOPE_AGENT) < target)
    __builtin_amdgcn_s_sleep(1);
}

// one wave: 64-batch x 64-col x 256-K slab, software-pipelined A loads.
// A = h f16 [64][1024]; accumulates into acc.
__device__ __forceinline__ void gemm_slab(const f16* __restrict__ A, int kbase,
                                          int l15, int q,
                                          const f16x8 (&Bf)[4][8], f32x4 (&acc)[4][4]) {
  f16x8 cur[8], nxt[8];
  const f16* ar0 = A + (size_t)l15 * H_ + kbase + q * 8;
#pragma unroll
  for (int kf = 0; kf < 8; ++kf) cur[kf] = *(const f16x8*)(ar0 + kf * 32);
#pragma unroll
  for (int mt = 0; mt < 4; ++mt) {
    if (mt < 3) {
      const f16* ar = A + (size_t)((mt + 1) * 16 + l15) * H_ + kbase + q * 8;
#pragma unroll
      for (int kf = 0; kf < 8; ++kf) nxt[kf] = *(const f16x8*)(ar + kf * 32);
    }
#pragma unroll
    for (int nt = 0; nt < 4; ++nt)
#pragma unroll
      for (int kf = 0; kf < 8; ++kf)
        acc[mt][nt] = __builtin_amdgcn_mfma_f32_16x16x32_f16(cur[kf], Bf[nt][kf],
                                                             acc[mt][nt], 0, 0, 0);
#pragma unroll
    for (int kf = 0; kf < 8; ++kf) cur[kf] = nxt[kf];
  }
}

__global__ __launch_bounds__(256, 1) void k_persist(
    const float* __restrict__ U0, const float* __restrict__ W1,
    const float* __restrict__ U1, const float* __restrict__ alpha0,
    const float* __restrict__ alpha1, const float* __restrict__ b1,
    const f16* __restrict__ wx, f16* h0r, f16* h1r, int* flg, float* out) {
  __shared__ float red[4][64][64];  // [kslice][mt*16+nt*4+r][lane]
  const int tid = threadIdx.x;
  const int w = tid >> 6, lane = tid & 63;
  const int q = lane >> 4, l15 = lane & 15;
  const int role = blockIdx.x >> 4, slice = blockIdx.x & 15;
  const int c0 = slice * 64;
  const int kbase = w * 256;

  int* flag0 = flg;
  int* flag1 = flg + 512;
  int* cons0 = flg + 1024;
  int* cons1 = flg + 1536;

  // weight slices into registers (one-time): B[k][n] = Wm[c][k]
  f16x8 BfA[4][8];  // role0: U0 ; role1: W1
  f16x8 BfB[4][8];  // role1: U1
  {
    const float* WmA = (role == 0) ? U0 : W1;
#pragma unroll
    for (int nt = 0; nt < 4; ++nt)
#pragma unroll
      for (int kf = 0; kf < 8; ++kf) {
        const float* p = WmA + (size_t)(c0 + nt * 16 + l15) * H_ + kbase + kf * 32 + q * 8;
        f16x8 v;
#pragma unroll
        for (int j = 0; j < 8; ++j) v[j] = (f16)p[j];
        BfA[nt][kf] = v;
      }
    if (role == 1) {
#pragma unroll
      for (int nt = 0; nt < 4; ++nt)
#pragma unroll
        for (int kf = 0; kf < 8; ++kf) {
          const float* p = U1 + (size_t)(c0 + nt * 16 + l15) * H_ + kbase + kf * 32 + q * 8;
          f16x8 v;
#pragma unroll
          for (int j = 0; j < 8; ++j) v[j] = (f16)p[j];
          BfB[nt][kf] = v;
        }
    }
  }

  float hst[16];  // persistent h state: wave w owns batches w*16..w*16+15
#pragma unroll
  for (int i = 0; i < 16; ++i) hst[i] = 0.f;
  float coef[4], biasv[4];
#pragma unroll
  for (int nt = 0; nt < 4; ++nt) {
    int c = c0 + nt * 16 + l15;
    coef[nt]  = ((role == 0) ? alpha0[c] : alpha1[c]) * 2.0f;  // alpha / tau
    biasv[nt] = (role == 1) ? b1[c] : 0.f;
  }

  if (role == 0) {
    for (int s = 0; s < 256; ++s) {
      // prefetch wx[s] before spinning (overlaps L3 latency)
      float wxv[16];
#pragma unroll
      for (int nt = 0; nt < 4; ++nt)
#pragma unroll
        for (int r = 0; r < 4; ++r)
          wxv[nt * 4 + r] =
              (float)wx[((size_t)s * B_ + (w * 16 + q * 4 + r)) * H_ + (c0 + nt * 16 + l15)];
      f32x4 acc[4][4] = {};
      if (s > 0) {
        if (tid == 0) {
          if (s >= 8) spin_ge(cons0 + (s - 8), 32);  // ring slot reusable
          spin_ge(flag0 + (s - 1), 16);              // h0(s-1) complete
          __builtin_amdgcn_fence(__ATOMIC_ACQUIRE, "agent");
        }
        __syncthreads();
        gemm_slab(h0r + (size_t)((s - 1) & 7) * B_ * H_, kbase, l15, q, BfA, acc);
      }
#pragma unroll
      for (int mt = 0; mt < 4; ++mt)
#pragma unroll
        for (int nt = 0; nt < 4; ++nt)
#pragma unroll
          for (int r = 0; r < 4; ++r)
            red[w][mt * 16 + nt * 4 + r][lane] = acc[mt][nt][r];
      __syncthreads();
      if (s > 0 && tid == 0)
        __hip_atomic_fetch_add(cons0 + (s - 1), 1, __ATOMIC_RELAXED, __HIP_MEMORY_SCOPE_AGENT);
      f16* hw = h0r + (size_t)(s & 7) * B_ * H_;
#pragma unroll
      for (int nt = 0; nt < 4; ++nt) {
        int c = c0 + nt * 16 + l15;
#pragma unroll
        for (int r = 0; r < 4; ++r) {
          int v = w * 16 + nt * 4 + r;
          float sum = red[0][v][lane] + red[1][v][lane] + red[2][v][lane] + red[3][v][lane]
                    + wxv[nt * 4 + r];
          float th = tanhf(sum);
          float h = hst[nt * 4 + r];
          h = h + coef[nt] * (th - h);
          hst[nt * 4 + r] = h;
          hw[(size_t)(w * 16 + q * 4 + r) * H_ + c] = (f16)h;
        }
      }
      __syncthreads();  // all waves' h stores drained (vmcnt(0) before barrier)
      if (tid == 0)
        __hip_atomic_fetch_add(flag0 + s, 1, __ATOMIC_RELEASE, __HIP_MEMORY_SCOPE_AGENT);
    }
  } else {
    for (int t = 0; t < 256; ++t) {
      if (tid == 0) {
        if (t >= 8) spin_ge(cons1 + (t - 8), 16);  // ring slot reusable
        spin_ge(flag0 + t, 16);                    // h0(t) complete
        if (t > 0) spin_ge(flag1 + (t - 1), 16);   // h1(t-1) complete
        __builtin_amdgcn_fence(__ATOMIC_ACQUIRE, "agent");
      }
      __syncthreads();
      f32x4 acc[4][4] = {};
      gemm_slab(h0r + (size_t)(t & 7) * B_ * H_, kbase, l15, q, BfA, acc);  // W1*h0(t)
      if (t > 0)
        gemm_slab(h1r + (size_t)((t - 1) & 7) * B_ * H_, kbase, l15, q, BfB, acc);  // +U1*h1(t-1)
#pragma unroll
      for (int mt = 0; mt < 4; ++mt)
#pragma unroll
        for (int nt = 0; nt < 4; ++nt)
#pragma unroll
          for (int r = 0; r < 4; ++r)
            red[w][mt * 16 + nt * 4 + r][lane] = acc[mt][nt][r];
      __syncthreads();
      if (tid == 0) {
        __hip_atomic_fetch_add(cons0 + t, 1, __ATOMIC_RELAXED, __HIP_MEMORY_SCOPE_AGENT);
        if (t > 0)
          __hip_atomic_fetch_add(cons1 + (t - 1), 1, __ATOMIC_RELAXED, __HIP_MEMORY_SCOPE_AGENT);
      }
      f16* hw = h1r + (size_t)(t & 7) * B_ * H_;
#pragma unroll
      for (int nt = 0; nt < 4; ++nt) {
        int c = c0 + nt * 16 + l15;
#pragma unroll
        for (int r = 0; r < 4; ++r) {
          int v = w * 16 + nt * 4 + r;
          float sum = red[0][v][lane] + red[1][v][lane] + red[2][v][lane] + red[3][v][lane]
                    + biasv[nt];
          float th = tanhf(sum);
          float h = hst[nt * 4 + r];
          h = h + coef[nt] * (th - h);
          hst[nt * 4 + r] = h;
          int b = w * 16 + q * 4 + r;
          hw[(size_t)b * H_ + c] = (f16)h;
          if (t == 255) out[(size_t)b * H_ + c] = h;
        }
      }
      __syncthreads();
      if (tid == 0)
        __hip_atomic_fetch_add(flag1 + t, 1, __ATOMIC_RELEASE, __HIP_MEMORY_SCOPE_AGENT);
    }
  }
}

extern "C" void kernel_launch(void* const* d_in, const int* in_sizes, int n_in,
                              void* d_out, int out_size, void* d_ws, size_t ws_size,
                              hipStream_t stream) {
  const float* x  = (const float*)d_in[0];
  const float* W0 = (const float*)d_in[1];
  const float* U0 = (const float*)d_in[2];
  const float* b0 = (const float*)d_in[3];
  const float* a0 = (const float*)d_in[4];
  const float* W1 = (const float*)d_in[5];
  const float* U1 = (const float*)d_in[6];
  const float* b1 = (const float*)d_in[7];
  const float* a1 = (const float*)d_in[8];
  char* ws = (char*)d_ws;
  f16*   wx  = (f16*)(ws + OFF_WX);
  f16*   h0r = (f16*)(ws + OFF_H0R);
  f16*   h1r = (f16*)(ws + OFF_H1R);
  int*   flg = (int*)(ws + OFF_FLG);
  float* out = (float*)d_out;

  hipMemsetAsync(flg, 0, 8192, stream);            // flags start at 0
  k_wx<<<256, 256, 0, stream>>>(x, W0, b0, wx);    // parallel Wx GEMM (f32 in)

  // plain launch: 32 WGs on an idle 256-CU device are always co-resident.
  k_persist<<<32, 256, 0, stream>>>(U0, W1, U1, a0, a1, b1, wx, h0r, h1r, flg, out);
}

// Round 4
// 3298.602 us; speedup vs baseline: 1.4026x; 1.0786x over previous
//
#include <hip/hip_runtime.h>

// Liquid NN: BATCH=64, SEQ=256, IN=512, HID=1024, 2 layers, tau=0.5.
// h0(t) = h0 + a0*2*(tanh(x_t@W0^T + b0 + h0@U0^T) - h0)
// h1(t) = h1 + a1*2*(tanh(h0(t)@W1^T + b1 + h1@U1^T) - h1)
// Output: h1(255) as f32 (64,1024).
//
// Weight-stationary f16 MFMA persistent kernel, 32 worker WGs pinned to ONE
// XCD (elected at runtime via HW_REG_XCC_ID voting) so the shared per-XCD L2
// is the coherence point: flags use RELAXED agent atomics (no buffer_wbl2 /
// no L2 invalidate on the recurrent critical path), consumers issue an
// L1-only `buffer_inv` before reading the h ring buffers.
//   role 0 (16 WGs): h0(s) = EMA(tanh(wx[s] + U0*h0(s-1)))
//   role 1 (16 WGs): h1(t) = EMA(tanh(b1 + W1*h0(t) + U1*h1(t-1)))

typedef _Float16 f16;
typedef _Float16 f16x8 __attribute__((ext_vector_type(8)));
typedef float    f32x4 __attribute__((ext_vector_type(4)));

#define B_  64
#define S_  256
#define IN_ 512
#define H_  1024

// ---- workspace layout (bytes) ----
static constexpr size_t OFF_WX  = 0;         // S*B*H f16 = 33554432
static constexpr size_t OFF_H0R = 33554432;  // 8*B*H f16 = 1048576
static constexpr size_t OFF_H1R = 34603008;  // 8*B*H f16 = 1048576
static constexpr size_t OFF_FLG = 35651584;  // 8 KB flags
// flag ints: flag0[256]@0, flag1[256]@512, cons0[256]@1024, cons1[256]@1536,
//            cnt[8]@1792, chosen@1800, ticket@1801

#define AGENT __HIP_MEMORY_SCOPE_AGENT

// ---------------- kernel: Wx = x @ W0^T + b0 (f32 in, f16 out) ----------------
__global__ __launch_bounds__(256) void k_wx(const float* __restrict__ x,
                                            const float* __restrict__ W0,
                                            const float* __restrict__ b0,
                                            f16* __restrict__ wx) {
  __shared__ uint4 xs[4096];  // 64 rows x 64 8-half chunks, chunk' = kc ^ (row&7)
  const int tid = threadIdx.x;
  const int w = tid >> 6, lane = tid & 63;
  const int q = lane >> 4, l15 = lane & 15;
  const int cslice = blockIdx.x & 15;
  const int rblock = blockIdx.x >> 4;
  const int c = cslice * 64 + w * 16 + l15;  // output column (D col = n)

  f16x8 Bf[16];  // B[k][n] = W0[c][k], lane holds k = kf*32 + q*8 + j
#pragma unroll
  for (int kf = 0; kf < 16; ++kf) {
    const float* p = W0 + (size_t)c * IN_ + kf * 32 + q * 8;
    f16x8 v;
#pragma unroll
    for (int j = 0; j < 8; ++j) v[j] = (f16)p[j];
    Bf[kf] = v;
  }
  const float bias = b0[c];

  for (int rt = 0; rt < 16; ++rt) {
    const int row0 = rblock * 1024 + rt * 64;
    __syncthreads();
#pragma unroll
    for (int it = 0; it < 16; ++it) {
      int g = it * 256 + tid;
      int r = g >> 6, kc = g & 63;
      const float* xp = x + (size_t)(row0 + r) * IN_ + kc * 8;
      float4 v0 = *(const float4*)xp;
      float4 v1 = *(const float4*)(xp + 4);
      f16x8 h;
      h[0] = (f16)v0.x; h[1] = (f16)v0.y; h[2] = (f16)v0.z; h[3] = (f16)v0.w;
      h[4] = (f16)v1.x; h[5] = (f16)v1.y; h[6] = (f16)v1.z; h[7] = (f16)v1.w;
      xs[r * 64 + (kc ^ (r & 7))] = *(uint4*)&h;
    }
    __syncthreads();
    f32x4 acc[4] = {};
#pragma unroll
    for (int mt = 0; mt < 4; ++mt) {
      const int r = mt * 16 + l15;
#pragma unroll
      for (int kf = 0; kf < 16; ++kf) {
        uint4 av = xs[r * 64 + ((kf * 4 + q) ^ (r & 7))];
        f16x8 a = *(f16x8*)&av;
        acc[mt] = __builtin_amdgcn_mfma_f32_16x16x32_f16(a, Bf[kf], acc[mt], 0, 0, 0);
      }
    }
#pragma unroll
    for (int mt = 0; mt < 4; ++mt) {
#pragma unroll
      for (int r = 0; r < 4; ++r) {
        int rowg = row0 + mt * 16 + q * 4 + r;  // = b*256 + t
        int b = rowg >> 8, t = rowg & 255;
        wx[((size_t)t * B_ + b) * H_ + c] = (f16)(acc[mt][r] + bias);
      }
    }
  }
}

// ---------------- persistent recurrent kernel ----------------
__device__ __forceinline__ void spin_ge(int* p, int target) {
  while (__hip_atomic_load(p, __ATOMIC_RELAXED, AGENT) < target)
    __builtin_amdgcn_s_sleep(1);
}
__device__ __forceinline__ void publish(int* p, int v) {
  __hip_atomic_fetch_add(p, v, __ATOMIC_RELAXED, AGENT);
}
__device__ __forceinline__ void l1_inv() {
  asm volatile("buffer_inv" ::: "memory");  // L1-only (no sc1): same-XCD L2 is coherent
}

// one wave: 64-batch x 64-col x 256-K slab, software-pipelined A loads.
__device__ __forceinline__ void gemm_slab(const f16* __restrict__ A, int kbase,
                                          int l15, int q,
                                          const f16x8 (&Bf)[4][8], f32x4 (&acc)[4][4]) {
  f16x8 cur[8], nxt[8];
  const f16* ar0 = A + (size_t)l15 * H_ + kbase + q * 8;
#pragma unroll
  for (int kf = 0; kf < 8; ++kf) cur[kf] = *(const f16x8*)(ar0 + kf * 32);
#pragma unroll
  for (int mt = 0; mt < 4; ++mt) {
    if (mt < 3) {
      const f16* ar = A + (size_t)((mt + 1) * 16 + l15) * H_ + kbase + q * 8;
#pragma unroll
      for (int kf = 0; kf < 8; ++kf) nxt[kf] = *(const f16x8*)(ar + kf * 32);
    }
#pragma unroll
    for (int nt = 0; nt < 4; ++nt)
#pragma unroll
      for (int kf = 0; kf < 8; ++kf)
        acc[mt][nt] = __builtin_amdgcn_mfma_f32_16x16x32_f16(cur[kf], Bf[nt][kf],
                                                             acc[mt][nt], 0, 0, 0);
#pragma unroll
    for (int kf = 0; kf < 8; ++kf) cur[kf] = nxt[kf];
  }
}

__global__ __launch_bounds__(256, 1) void k_persist(
    const float* __restrict__ U0, const float* __restrict__ W1,
    const float* __restrict__ U1, const float* __restrict__ alpha0,
    const float* __restrict__ alpha1, const float* __restrict__ b1,
    const f16* __restrict__ wx, f16* h0r, f16* h1r, int* flg, float* out) {
  __shared__ float red[4][64][64];  // [kslice][mt*16+nt*4+r][lane]; [0][0][0] doubles as bcast
  const int tid = threadIdx.x;
  const int w = tid >> 6, lane = tid & 63;
  const int q = lane >> 4, l15 = lane & 15;

  int* flag0 = flg;
  int* flag1 = flg + 512;
  int* cons0 = flg + 1024;
  int* cons1 = flg + 1536;
  int* cnt   = flg + 1792;
  int* chosen = flg + 1800;
  int* ticket = flg + 1801;

  // ---- elect one XCD; 32 workers there; everyone else exits ----
  // HW_REG_XCC_ID: id=20, offset=0, size=4 -> imm = 20 | (3<<11) = 6164
  const int xcc = (int)__builtin_amdgcn_s_getreg(6164) & 7;
  int* sh = (int*)&red[0][0][0];
  if (tid == 0) {
    publish(cnt + xcc, 1);
    if (blockIdx.x == 0) {
      int sel = -1;
      while (sel < 0) {
        for (int i = 0; i < 8; ++i)
          if (__hip_atomic_load(cnt + i, __ATOMIC_RELAXED, AGENT) >= 32) { sel = i; break; }
        if (sel < 0) __builtin_amdgcn_s_sleep(1);
      }
      publish(chosen, sel + 1);
    }
    int ch;
    while ((ch = __hip_atomic_load(chosen, __ATOMIC_RELAXED, AGENT)) == 0)
      __builtin_amdgcn_s_sleep(1);
    int my = -1;
    if (xcc == ch - 1) my = __hip_atomic_fetch_add(ticket, 1, __ATOMIC_RELAXED, AGENT);
    sh[0] = my;
  }
  __syncthreads();
  const int myid = sh[0];
  __syncthreads();
  if (myid < 0 || myid >= 32) return;
  const int role = myid >> 4, slice = myid & 15;
  const int c0 = slice * 64;
  const int kbase = w * 256;

  // ---- weight slices into registers (one-time): B[k][n] = Wm[c][k] ----
  f16x8 BfA[4][8];  // role0: U0 ; role1: W1
  f16x8 BfB[4][8];  // role1: U1
  {
    const float* WmA = (role == 0) ? U0 : W1;
#pragma unroll
    for (int nt = 0; nt < 4; ++nt)
#pragma unroll
      for (int kf = 0; kf < 8; ++kf) {
        const float* p = WmA + (size_t)(c0 + nt * 16 + l15) * H_ + kbase + kf * 32 + q * 8;
        f16x8 v;
#pragma unroll
        for (int j = 0; j < 8; ++j) v[j] = (f16)p[j];
        BfA[nt][kf] = v;
      }
    if (role == 1) {
#pragma unroll
      for (int nt = 0; nt < 4; ++nt)
#pragma unroll
        for (int kf = 0; kf < 8; ++kf) {
          const float* p = U1 + (size_t)(c0 + nt * 16 + l15) * H_ + kbase + kf * 32 + q * 8;
          f16x8 v;
#pragma unroll
          for (int j = 0; j < 8; ++j) v[j] = (f16)p[j];
          BfB[nt][kf] = v;
        }
    }
  }

  float hst[16];
#pragma unroll
  for (int i = 0; i < 16; ++i) hst[i] = 0.f;
  float coef[4], biasv[4];
#pragma unroll
  for (int nt = 0; nt < 4; ++nt) {
    int c = c0 + nt * 16 + l15;
    coef[nt]  = ((role == 0) ? alpha0[c] : alpha1[c]) * 2.0f;  // alpha / tau
    biasv[nt] = (role == 1) ? b1[c] : 0.f;
  }

  if (role == 0) {
    for (int s = 0; s < 256; ++s) {
      float wxv[16];  // prefetch wx[s] (immutable, L1-safe) before the spin
#pragma unroll
      for (int nt = 0; nt < 4; ++nt)
#pragma unroll
        for (int r = 0; r < 4; ++r)
          wxv[nt * 4 + r] =
              (float)wx[((size_t)s * B_ + (w * 16 + q * 4 + r)) * H_ + (c0 + nt * 16 + l15)];
      f32x4 acc[4][4] = {};
      if (s > 0) {
        if (tid == 0) spin_ge(flag0 + (s - 1), 16);              // h0(s-1) ready
        if (tid == 1 && s >= 8) spin_ge(cons0 + (s - 8), 32);    // ring slot free
        __syncthreads();
        l1_inv();
        gemm_slab(h0r + (size_t)((s - 1) & 7) * B_ * H_, kbase, l15, q, BfA, acc);
      }
#pragma unroll
      for (int mt = 0; mt < 4; ++mt)
#pragma unroll
        for (int nt = 0; nt < 4; ++nt)
#pragma unroll
          for (int r = 0; r < 4; ++r)
            red[w][mt * 16 + nt * 4 + r][lane] = acc[mt][nt][r];
      __syncthreads();
      if (s > 0 && tid == 0) publish(cons0 + (s - 1), 1);
      f16* hw = h0r + (size_t)(s & 7) * B_ * H_;
#pragma unroll
      for (int nt = 0; nt < 4; ++nt) {
        int c = c0 + nt * 16 + l15;
#pragma unroll
        for (int r = 0; r < 4; ++r) {
          int v = w * 16 + nt * 4 + r;
          float sum = red[0][v][lane] + red[1][v][lane] + red[2][v][lane] + red[3][v][lane]
                    + wxv[nt * 4 + r];
          float th = tanhf(sum);
          float h = hst[nt * 4 + r];
          h = h + coef[nt] * (th - h);
          hst[nt * 4 + r] = h;
          hw[(size_t)(w * 16 + q * 4 + r) * H_ + c] = (f16)h;
        }
      }
      __syncthreads();  // vmcnt(0): h stores in shared L2 before flag moves
      if (tid == 0) publish(flag0 + s, 1);
    }
  } else {
    for (int t = 0; t < 256; ++t) {
      if (tid == 0) spin_ge(flag0 + t, 16);                     // h0(t) ready
      if (tid == 1 && t > 0) spin_ge(flag1 + (t - 1), 16);      // h1(t-1) ready
      if (tid == 2 && t >= 8) spin_ge(cons1 + (t - 8), 16);     // ring slot free
      __syncthreads();
      l1_inv();
      f32x4 acc[4][4] = {};
      gemm_slab(h0r + (size_t)(t & 7) * B_ * H_, kbase, l15, q, BfA, acc);  // W1*h0(t)
      if (t > 0)
        gemm_slab(h1r + (size_t)((t - 1) & 7) * B_ * H_, kbase, l15, q, BfB, acc);  // +U1*h1(t-1)
#pragma unroll
      for (int mt = 0; mt < 4; ++mt)
#pragma unroll
        for (int nt = 0; nt < 4; ++nt)
#pragma unroll
          for (int r = 0; r < 4; ++r)
            red[w][mt * 16 + nt * 4 + r][lane] = acc[mt][nt][r];
      __syncthreads();
      if (tid == 0) {
        publish(cons0 + t, 1);
        if (t > 0) publish(cons1 + (t - 1), 1);
      }
      f16* hw = h1r + (size_t)(t & 7) * B_ * H_;
#pragma unroll
      for (int nt = 0; nt < 4; ++nt) {
        int c = c0 + nt * 16 + l15;
#pragma unroll
        for (int r = 0; r < 4; ++r) {
          int v = w * 16 + nt * 4 + r;
          float sum = red[0][v][lane] + red[1][v][lane] + red[2][v][lane] + red[3][v][lane]
                    + biasv[nt];
          float th = tanhf(sum);
          float h = hst[nt * 4 + r];
          h = h + coef[nt] * (th - h);
          hst[nt * 4 + r] = h;
          int b = w * 16 + q * 4 + r;
          hw[(size_t)b * H_ + c] = (f16)h;
          if (t == 255) out[(size_t)b * H_ + c] = h;
        }
      }
      __syncthreads();
      if (tid == 0) publish(flag1 + t, 1);
    }
  }
}

extern "C" void kernel_launch(void* const* d_in, const int* in_sizes, int n_in,
                              void* d_out, int out_size, void* d_ws, size_t ws_size,
                              hipStream_t stream) {
  const float* x  = (const float*)d_in[0];
  const float* W0 = (const float*)d_in[1];
  const float* U0 = (const float*)d_in[2];
  const float* b0 = (const float*)d_in[3];
  const float* a0 = (const float*)d_in[4];
  const float* W1 = (const float*)d_in[5];
  const float* U1 = (const float*)d_in[6];
  const float* b1 = (const float*)d_in[7];
  const float* a1 = (const float*)d_in[8];
  char* ws = (char*)d_ws;
  f16*   wx  = (f16*)(ws + OFF_WX);
  f16*   h0r = (f16*)(ws + OFF_H0R);
  f16*   h1r = (f16*)(ws + OFF_H1R);
  int*   flg = (int*)(ws + OFF_FLG);
  float* out = (float*)d_out;

  hipMemsetAsync(flg, 0, 8192, stream);            // flags/election start at 0
  k_wx<<<256, 256, 0, stream>>>(x, W0, b0, wx);    // parallel Wx GEMM

  // 256 blocks: every XCD gets >=32 by pigeonhole; workers self-select onto one.
  k_persist<<<256, 256, 0, stream>>>(U0, W1, U1, a0, a1, b1, wx, h0r, h1r, flg, out);
}

// Round 7
// 3246.841 us; speedup vs baseline: 1.4250x; 1.0159x over previous
//
#include <hip/hip_runtime.h>

// Liquid NN: BATCH=64, SEQ=256, IN=512, HID=1024, 2 layers, tau=0.5.
// h0(t) = h0 + a0*2*(tanh(x_t@W0^T + b0 + h0@U0^T) - h0)
// h1(t) = h1 + a1*2*(tanh(h0(t)@W1^T + b1 + h1@U1^T) - h1)
// Output: h1(255) as f32 (64,1024).
//
// 32 worker WGs elected onto ONE XCD (R4-validated election + FETCH collapse).
// Sync primitives are R4-validated AGENT atomics only (no inline-asm memory ops):
//   - per-producer flag WORDS: flagXw[j] = steps completed by WG j, published by
//     a single AGENT relaxed atomic STORE (no RMW -> no 16-way line contention)
//   - dependency poll: wave-0 16-lane vector AGENT atomic load (one 64B line =
//     one round trip); ring-slack poll runs concurrently in wave 1
//   - l1_inv (L1-only) before h-ring slab reads; producer h stores are drained
//     by __syncthreads (vmcnt0) before the flag store
//   - lockstep protocol: role0 step s waits flag0w[*]>=s, flag1w[*]>=s-7;
//     role1 step t waits flag0w[*]>=t+1, flag1w[*]>=t  (depth-8 rings safe)
// role 0 (16 WGs): h0(s) = EMA(tanh(wx[s] + U0*h0(s-1)))
// role 1 (16 WGs): h1(t) = EMA(tanh(b1 + W1*h0(t) + U1*h1(t-1)))
// Epilogue: XOR-swizzled LDS transpose (aligned(16) -> legal b128), each thread
// owns one batch row x 16 consecutive cols -> 2x b128 h stores, 2x b128 wx loads.

typedef _Float16 f16;
typedef _Float16 f16x8 __attribute__((ext_vector_type(8)));
typedef float    f32x4 __attribute__((ext_vector_type(4)));

#define B_  64
#define S_  256
#define IN_ 512
#define H_  1024

static constexpr size_t OFF_WX  = 0;         // S*B*H f16 = 33554432
static constexpr size_t OFF_H0R = 33554432;  // 8*B*H f16 = 1048576
static constexpr size_t OFF_H1R = 34603008;  // 8*B*H f16 = 1048576
static constexpr size_t OFF_FLG = 35651584;  // flags
// flg ints: flag0w[16]@0 (line 0), flag1w[16]@16 (line 1),
//           cnt[8]@32, chosen@40, ticket@41 (line 2)

#define AGENT __HIP_MEMORY_SCOPE_AGENT

// ---------------- kernel: Wx = x @ W0^T + b0 (f32 in, f16 out) ----------------
__global__ __launch_bounds__(256) void k_wx(const float* __restrict__ x,
                                            const float* __restrict__ W0,
                                            const float* __restrict__ b0,
                                            f16* __restrict__ wx) {
  __shared__ uint4 xs[4096];  // 64 rows x 64 8-half chunks, chunk' = kc ^ (row&7)
  const int tid = threadIdx.x;
  const int w = tid >> 6, lane = tid & 63;
  const int q = lane >> 4, l15 = lane & 15;
  const int cslice = blockIdx.x & 15;
  const int rblock = blockIdx.x >> 4;  // 0..31
  const int c = cslice * 64 + w * 16 + l15;

  f16x8 Bf[16];  // B[k][n] = W0[c][k], lane holds k = kf*32 + q*8 + j
#pragma unroll
  for (int kf = 0; kf < 16; ++kf) {
    const float* p = W0 + (size_t)c * IN_ + kf * 32 + q * 8;
    f16x8 v;
#pragma unroll
    for (int j = 0; j < 8; ++j) v[j] = (f16)p[j];
    Bf[kf] = v;
  }
  const float bias = b0[c];

  for (int rt = 0; rt < 8; ++rt) {
    const int row0 = rblock * 512 + rt * 64;
    __syncthreads();
#pragma unroll
    for (int it = 0; it < 16; ++it) {
      int g = it * 256 + tid;
      int r = g >> 6, kc = g & 63;
      const float* xp = x + (size_t)(row0 + r) * IN_ + kc * 8;
      float4 v0 = *(const float4*)xp;
      float4 v1 = *(const float4*)(xp + 4);
      f16x8 h;
      h[0] = (f16)v0.x; h[1] = (f16)v0.y; h[2] = (f16)v0.z; h[3] = (f16)v0.w;
      h[4] = (f16)v1.x; h[5] = (f16)v1.y; h[6] = (f16)v1.z; h[7] = (f16)v1.w;
      xs[r * 64 + (kc ^ (r & 7))] = *(uint4*)&h;
    }
    __syncthreads();
    f32x4 acc[4] = {};
#pragma unroll
    for (int mt = 0; mt < 4; ++mt) {
      const int r = mt * 16 + l15;
#pragma unroll
      for (int kf = 0; kf < 16; ++kf) {
        uint4 av = xs[r * 64 + ((kf * 4 + q) ^ (r & 7))];
        f16x8 a = *(f16x8*)&av;
        acc[mt] = __builtin_amdgcn_mfma_f32_16x16x32_f16(a, Bf[kf], acc[mt], 0, 0, 0);
      }
    }
#pragma unroll
    for (int mt = 0; mt < 4; ++mt) {
#pragma unroll
      for (int r = 0; r < 4; ++r) {
        int rowg = row0 + mt * 16 + q * 4 + r;  // = b*256 + t
        int b = rowg >> 8, t = rowg & 255;
        wx[((size_t)t * B_ + b) * H_ + c] = (f16)(acc[mt][r] + bias);
      }
    }
  }
}

// ---------------- persistent recurrent kernel ----------------
__device__ __forceinline__ void l1_inv() {
  asm volatile("buffer_inv" ::: "memory");  // L1-only: elected-XCD L2 is coherence pt
}

// whole-wave vector poll: lanes 0-15 wait f[lane] >= tgt (one 64B line / round trip)
__device__ __forceinline__ void pollw(const int* f, int tgt, int lane) {
  bool pend = (lane < 16) && (tgt > 0);
  const int* p = f + (lane & 15);
  while (__ballot(pend)) {
    if (pend && __hip_atomic_load((int*)p, __ATOMIC_RELAXED, AGENT) >= tgt)
      pend = false;
  }
}

// one wave: 64-batch x 64-col x 256-K slab, software-pipelined A loads.
__device__ __forceinline__ void gemm_slab(const f16* __restrict__ A, int kbase,
                                          int l15, int q,
                                          const f16x8 (&Bf)[4][8], f32x4 (&acc)[4][4]) {
  f16x8 cur[8], nxt[8];
  const f16* ar0 = A + (size_t)l15 * H_ + kbase + q * 8;
#pragma unroll
  for (int kf = 0; kf < 8; ++kf) cur[kf] = *(const f16x8*)(ar0 + kf * 32);
#pragma unroll
  for (int mt = 0; mt < 4; ++mt) {
    if (mt < 3) {
      const f16* ar = A + (size_t)((mt + 1) * 16 + l15) * H_ + kbase + q * 8;
#pragma unroll
      for (int kf = 0; kf < 8; ++kf) nxt[kf] = *(const f16x8*)(ar + kf * 32);
    }
#pragma unroll
    for (int nt = 0; nt < 4; ++nt)
#pragma unroll
      for (int kf = 0; kf < 8; ++kf)
        acc[mt][nt] = __builtin_amdgcn_mfma_f32_16x16x32_f16(cur[kf], Bf[nt][kf],
                                                             acc[mt][nt], 0, 0, 0);
#pragma unroll
    for (int kf = 0; kf < 8; ++kf) cur[kf] = nxt[kf];
  }
}

__global__ __launch_bounds__(256, 1) void k_persist(
    const float* __restrict__ U0, const float* __restrict__ W1,
    const float* __restrict__ U1, const float* __restrict__ alpha0,
    const float* __restrict__ alpha1, const float* __restrict__ b1,
    const f16* __restrict__ wx, f16* h0r, f16* h1r, int* flg, float* out) {
  // red[ks][i][col]: D[m][n] of K-slice ks, m=(i>>4)*16+(col>>4)*4+(i&3),
  // n=((i>>2)&3)*16+(col&15), stored XOR-swizzled at col' = col ^ ((i&3)<<2).
  // aligned(16): epilogue does b128 LDS reads (under-aligned b128 = fault).
  __shared__ __attribute__((aligned(16))) float red[4][64][64];  // exactly 64 KiB
  const int tid = threadIdx.x;
  const int w = tid >> 6, lane = tid & 63;
  const int q = lane >> 4, l15 = lane & 15;

  int* flag0w = flg;        // word j = steps completed by role0 WG j
  int* flag1w = flg + 16;   // word j = steps completed by role1 WG j
  int* cnt    = flg + 32;
  int* chosen = flg + 40;
  int* ticket = flg + 41;

  // ---- elect one XCD; 32 workers there; everyone else exits (R4-validated) ----
  const int xcc = (int)__builtin_amdgcn_s_getreg(6164) & 7;  // HW_REG_XCC_ID
  int* sh = (int*)&red[0][0][0];
  if (tid == 0) {
    __hip_atomic_fetch_add(cnt + xcc, 1, __ATOMIC_RELAXED, AGENT);
    if (blockIdx.x == 0) {
      int sel = -1;
      while (sel < 0) {
        for (int i = 0; i < 8; ++i)
          if (__hip_atomic_load(cnt + i, __ATOMIC_RELAXED, AGENT) >= 32) { sel = i; break; }
        if (sel < 0) __builtin_amdgcn_s_sleep(1);
      }
      __hip_atomic_fetch_add(chosen, sel + 1, __ATOMIC_RELAXED, AGENT);
    }
    int ch;
    while ((ch = __hip_atomic_load(chosen, __ATOMIC_RELAXED, AGENT)) == 0)
      __builtin_amdgcn_s_sleep(1);
    int my = -1;
    if (xcc == ch - 1) my = __hip_atomic_fetch_add(ticket, 1, __ATOMIC_RELAXED, AGENT);
    sh[0] = my;
  }
  __syncthreads();
  const int myid = sh[0];
  __syncthreads();
  if (myid < 0 || myid >= 32) return;
  const int role = myid >> 4, slice = myid & 15;
  const int c0 = slice * 64;
  const int kbase = w * 256;

  // ---- weight slices into registers: B[k][n] = Wm[c][k] ----
  f16x8 BfA[4][8];  // role0: U0 ; role1: W1
  f16x8 BfB[4][8];  // role1: U1
  {
    const float* WmA = (role == 0) ? U0 : W1;
#pragma unroll
    for (int nt = 0; nt < 4; ++nt)
#pragma unroll
      for (int kf = 0; kf < 8; ++kf) {
        const float* p = WmA + (size_t)(c0 + nt * 16 + l15) * H_ + kbase + kf * 32 + q * 8;
        f16x8 v;
#pragma unroll
        for (int j = 0; j < 8; ++j) v[j] = (f16)p[j];
        BfA[nt][kf] = v;
      }
    if (role == 1) {
#pragma unroll
      for (int nt = 0; nt < 4; ++nt)
#pragma unroll
        for (int kf = 0; kf < 8; ++kf) {
          const float* p = U1 + (size_t)(c0 + nt * 16 + l15) * H_ + kbase + kf * 32 + q * 8;
          f16x8 v;
#pragma unroll
          for (int j = 0; j < 8; ++j) v[j] = (f16)p[j];
          BfB[nt][kf] = v;
        }
    }
  }

  // ---- epilogue ownership: thread owns batch row bown, cols cbase..cbase+15 ----
  const int bown = w * 16 + (lane & 15);
  const int gq   = lane >> 4;
  const int iidx = w * 16 + gq * 4 + (lane & 3);  // fixed LDS row
  const int lsb  = ((lane >> 2) & 3) * 16;        // fixed logical col base
  const int swz  = (lane & 3) << 2;               // read-side XOR (row&3 == lane&3)
  const int cbase = c0 + gq * 16;

  f16x8 cfh[2], bsh[2];  // packed alpha*2 and bias for the 16 owned cols
  {
    const float* ap = ((role == 0) ? alpha0 : alpha1) + cbase;
    const float* bp = b1 + cbase;
    f16x8 t0, t1, u0, u1;
#pragma unroll
    for (int j = 0; j < 8; ++j) {
      t0[j] = (f16)(ap[j] * 2.0f);
      t1[j] = (f16)(ap[8 + j] * 2.0f);
      u0[j] = (f16)bp[j];
      u1[j] = (f16)bp[8 + j];
    }
    cfh[0] = t0; cfh[1] = t1; bsh[0] = u0; bsh[1] = u1;
  }

  float hst[16];
#pragma unroll
  for (int i = 0; i < 16; ++i) hst[i] = 0.f;

  if (role == 0) {
    for (int s = 0; s < 256; ++s) {
      // prefetch wx[s] for owned (b, cols): 2 x b128, in flight during the poll
      const f16* wp = wx + ((size_t)s * B_ + bown) * H_ + cbase;
      f16x8 wxa = *(const f16x8*)wp;
      f16x8 wxb = *(const f16x8*)(wp + 8);
      f32x4 acc[4][4] = {};
      if (s > 0) {
        if (w == 0) pollw(flag0w, s, lane);              // peers finished s-1
        if (w == 1) pollw(flag1w, s - 7, lane);          // ring slot s&7 free
        __syncthreads();
        l1_inv();
        gemm_slab(h0r + (size_t)((s - 1) & 7) * B_ * H_, kbase, l15, q, BfA, acc);
      }
#pragma unroll
      for (int mt = 0; mt < 4; ++mt)
#pragma unroll
        for (int nt = 0; nt < 4; ++nt)
#pragma unroll
          for (int r = 0; r < 4; ++r)
            red[w][mt * 16 + nt * 4 + r][lane ^ (r << 2)] = acc[mt][nt][r];
      __syncthreads();
      float vs[16];
#pragma unroll
      for (int ks = 0; ks < 4; ++ks)
#pragma unroll
        for (int ch = 0; ch < 4; ++ch) {
          f32x4 v = *(const f32x4*)&red[ks][iidx][lsb + ((ch << 2) ^ swz)];
          if (ks == 0) {
            vs[ch*4+0] = v[0]; vs[ch*4+1] = v[1]; vs[ch*4+2] = v[2]; vs[ch*4+3] = v[3];
          } else {
            vs[ch*4+0] += v[0]; vs[ch*4+1] += v[1]; vs[ch*4+2] += v[2]; vs[ch*4+3] += v[3];
          }
        }
      f16* hw = h0r + (size_t)(s & 7) * B_ * H_ + (size_t)bown * H_ + cbase;
      f16x8 o0, o1;
#pragma unroll
      for (int j = 0; j < 16; ++j) {
        float wxv = (float)((j < 8) ? wxa[j] : wxb[j - 8]);
        float cf  = (float)((j < 8) ? cfh[0][j] : cfh[1][j - 8]);
        float th = tanhf(vs[j] + wxv);
        float h = hst[j];
        h = h + cf * (th - h);
        hst[j] = h;
        if (j < 8) o0[j] = (f16)h; else o1[j - 8] = (f16)h;
      }
      *(f16x8*)hw = o0;
      *(f16x8*)(hw + 8) = o1;
      __syncthreads();  // vmcnt(0) per wave: h stores in shared L2 before flag
      if (tid == 0)
        __hip_atomic_store(flag0w + slice, s + 1, __ATOMIC_RELAXED, AGENT);
    }
  } else {
    for (int t = 0; t < 256; ++t) {
      if (w == 0) pollw(flag0w, t + 1, lane);            // h0(t) ready
      if (w == 1) pollw(flag1w, t, lane);                // peers finished t-1 (+ring)
      __syncthreads();
      l1_inv();
      f32x4 acc[4][4] = {};
      gemm_slab(h0r + (size_t)(t & 7) * B_ * H_, kbase, l15, q, BfA, acc);  // W1*h0(t)
      if (t > 0)
        gemm_slab(h1r + (size_t)((t - 1) & 7) * B_ * H_, kbase, l15, q, BfB, acc);
#pragma unroll
      for (int mt = 0; mt < 4; ++mt)
#pragma unroll
        for (int nt = 0; nt < 4; ++nt)
#pragma unroll
          for (int r = 0; r < 4; ++r)
            red[w][mt * 16 + nt * 4 + r][lane ^ (r << 2)] = acc[mt][nt][r];
      __syncthreads();
      float vs[16];
#pragma unroll
      for (int ks = 0; ks < 4; ++ks)
#pragma unroll
        for (int ch = 0; ch < 4; ++ch) {
          f32x4 v = *(const f32x4*)&red[ks][iidx][lsb + ((ch << 2) ^ swz)];
          if (ks == 0) {
            vs[ch*4+0] = v[0]; vs[ch*4+1] = v[1]; vs[ch*4+2] = v[2]; vs[ch*4+3] = v[3];
          } else {
            vs[ch*4+0] += v[0]; vs[ch*4+1] += v[1]; vs[ch*4+2] += v[2]; vs[ch*4+3] += v[3];
          }
        }
      f16* hw = h1r + (size_t)(t & 7) * B_ * H_ + (size_t)bown * H_ + cbase;
      f16x8 o0, o1;
#pragma unroll
      for (int j = 0; j < 16; ++j) {
        float bs = (float)((j < 8) ? bsh[0][j] : bsh[1][j - 8]);
        float cf = (float)((j < 8) ? cfh[0][j] : cfh[1][j - 8]);
        float th = tanhf(vs[j] + bs);
        float h = hst[j];
        h = h + cf * (th - h);
        hst[j] = h;
        if (j < 8) o0[j] = (f16)h; else o1[j - 8] = (f16)h;
      }
      *(f16x8*)hw = o0;
      *(f16x8*)(hw + 8) = o1;
      if (t == 255) {
        float* op = out + (size_t)bown * H_ + cbase;
#pragma unroll
        for (int ch = 0; ch < 4; ++ch) {
          float4 vv;
          vv.x = hst[ch*4+0]; vv.y = hst[ch*4+1]; vv.z = hst[ch*4+2]; vv.w = hst[ch*4+3];
          *(float4*)(op + ch * 4) = vv;
        }
      }
      __syncthreads();
      if (tid == 0)
        __hip_atomic_store(flag1w + slice, t + 1, __ATOMIC_RELAXED, AGENT);
    }
  }
}

// Swizzle identity: writer lane L stores logical col L at physical col
// L ^ ((i&3)<<2). Reader (row iidx, iidx&3 == lane&3) reads physical
// lsb + ((ch<<2) ^ ((lane&3)<<2)) + nn, which un-XORs to logical
// lsb + ch*4 + nn. Writes are lane-permutations (conflict-free); b128 reads
// spread across all 32 banks (conflict-free).

extern "C" void kernel_launch(void* const* d_in, const int* in_sizes, int n_in,
                              void* d_out, int out_size, void* d_ws, size_t ws_size,
                              hipStream_t stream) {
  const float* x  = (const float*)d_in[0];
  const float* W0 = (const float*)d_in[1];
  const float* U0 = (const float*)d_in[2];
  const float* b0 = (const float*)d_in[3];
  const float* a0 = (const float*)d_in[4];
  const float* W1 = (const float*)d_in[5];
  const float* U1 = (const float*)d_in[6];
  const float* b1 = (const float*)d_in[7];
  const float* a1 = (const float*)d_in[8];
  char* ws = (char*)d_ws;
  f16*   wx  = (f16*)(ws + OFF_WX);
  f16*   h0r = (f16*)(ws + OFF_H0R);
  f16*   h1r = (f16*)(ws + OFF_H1R);
  int*   flg = (int*)(ws + OFF_FLG);
  float* out = (float*)d_out;

  hipMemsetAsync(flg, 0, 8192, stream);            // flags/election start at 0
  k_wx<<<512, 256, 0, stream>>>(x, W0, b0, wx);    // parallel Wx GEMM

  // 256 blocks: every XCD gets >=32 by pigeonhole; workers self-select onto one.
  k_persist<<<256, 256, 0, stream>>>(U0, W1, U1, a0, a1, b1, wx, h0r, h1r, flg, out);
}